// Round 13
// baseline (417.961 us; speedup 1.0000x reference)
//
#include <hip/hip_runtime.h>
#include <hip/hip_bf16.h>

#define NN 200000
#define NE 800000
#define NG 8192
#define HD 128
#define OD 256

typedef __attribute__((ext_vector_type(8))) short bf16x8;
typedef __attribute__((ext_vector_type(4))) float f32x4;
typedef __attribute__((ext_vector_type(2))) float f32x2;

__device__ inline unsigned short f2bf(float x) {
    unsigned u = __float_as_uint(x);
    unsigned r = u + 0x7FFFu + ((u >> 16) & 1u);
    return (unsigned short)(r >> 16);
}
__device__ inline float b2f(unsigned short u) {
    return __uint_as_float((unsigned)u << 16);
}
// unpack u32 holding two bf16 (lo,hi) -> f32x2
__device__ inline f32x2 up2(unsigned u) {
    f32x2 r;
    r.x = __uint_as_float(u << 16);
    r.y = __uint_as_float(u & 0xFFFF0000u);
    return r;
}

// ---------------- setup: P + T tables + weight transpose + init (cursor/gstart/gend) ----------------
// ranges: [0,22656) P, [22656,26496) T, [26496,124800) Wt, [124800,324800) init
__global__ void setup_kernel(
    const float* __restrict__ e0, const float* __restrict__ e1, const float* __restrict__ e2,
    const float* __restrict__ e3, const float* __restrict__ e4, const float* __restrict__ e5,
    const float* __restrict__ e6, const float* __restrict__ e7, const float* __restrict__ e8,
    const float* __restrict__ node_w, const float* __restrict__ node_b,
    const float* __restrict__ ebond, const float* __restrict__ estereo, const float* __restrict__ econj,
    const float* __restrict__ edge_w, const float* __restrict__ edge_b,
    const float* __restrict__ cw1, const float* __restrict__ cw2,
    float* __restrict__ P, float* __restrict__ T, unsigned short* __restrict__ Wt,
    int* __restrict__ cursor, int* __restrict__ gstart, int* __restrict__ gend)
{
    int idx = blockIdx.x * 256 + threadIdx.x;
    const int NP = 177 * 128;          // 22656
    const int NT = NP + 30 * 128;      // 26496
    const int NW = NT + 6 * 16384;     // 124800
    if (idx < NP) {
        int row = idx >> 7, j = idx & 127;
        const int offs[10] = {0,119,128,139,151,160,165,173,175,177};
        int i = 0;
        while (row >= offs[i+1]) ++i;
        int lv = row - offs[i];
        const float* emb;
        switch (i) {
            case 0: emb = e0; break; case 1: emb = e1; break; case 2: emb = e2; break;
            case 3: emb = e3; break; case 4: emb = e4; break; case 5: emb = e5; break;
            case 6: emb = e6; break; case 7: emb = e7; break; default: emb = e8; break;
        }
        float acc = (i == 0) ? node_b[j] : 0.f;
        const float* wcol = node_w + (i * 32) * 128 + j;
        #pragma unroll
        for (int d = 0; d < 32; ++d) acc += emb[lv*32 + d] * wcol[d*128];
        P[idx] = acc;
    } else if (idx < NT) {
        int k = idx - NP;
        int row = k >> 7, j = k & 127;
        int i, lv; const float* emb;
        if (row < 22)      { i = 0; lv = row;      emb = ebond;   }
        else if (row < 28) { i = 1; lv = row - 22; emb = estereo; }
        else               { i = 2; lv = row - 28; emb = econj;   }
        float acc = (i == 0) ? edge_b[j] : 0.f;
        const float* wcol = edge_w + (i * 32) * 128 + j;
        #pragma unroll
        for (int d = 0; d < 32; ++d) acc += emb[lv*32 + d] * wcol[d*128];
        T[k] = acc;
    } else if (idx < NW) {
        int w = idx - NT;
        int m = w >> 14;
        int rem = w & 16383;
        int j = rem >> 7, k = rem & 127;
        int l = m >> 1;
        const float* W = ((m & 1) ? cw2 : cw1) + (size_t)l * 16384;
        Wt[w] = f2bf(W[k * 128 + j]);
    } else {
        int k = idx - NW;
        if (k < NN) cursor[k] = k << 5;
        if (k < NG) { gstart[k] = NN; gend[k] = 0; }
    }
}

// ---------------- mega-dispatch: scatter (overlapped) + Tcb combine + embed + bounds ----------------
// scatter blocks FIRST so their latency-bound waves coexist with embed's streaming waves.
#define SC_NB  1563                   // ceil((NE/2)/256)
#define TCB_B0 SC_NB
#define TCB_NB 132
#define EMB_B0 (TCB_B0 + TCB_NB)      // 1695
#define EMB_NB (NN / 8)               // 25000
#define BND_B0 (EMB_B0 + EMB_NB)      // 26695
#define BND_NB 782
__global__ __launch_bounds__(256) void embed_scatter_kernel(
    const float* __restrict__ T, unsigned short* __restrict__ Tcb,
    const int* __restrict__ x, const float* __restrict__ P, unsigned short* __restrict__ h,
    const int* __restrict__ bid, int* __restrict__ gstart, int* __restrict__ gend,
    const int* __restrict__ src, const int* __restrict__ dst, const int* __restrict__ eattr,
    int* __restrict__ cursor, int* __restrict__ ell)
{
    if (blockIdx.x < SC_NB) {
        // ELL scatter: 2 edges per thread (strided halves); ell[slot] = src | cidx<<18
        int e0 = blockIdx.x * 256 + threadIdx.x;
        if (e0 >= NE / 2) return;
        #pragma unroll
        for (int k = 0; k < 2; ++k) {
            int e = e0 + k * (NE / 2);
            int d = dst[e];
            int p = atomicAdd(&cursor[d], 1);
            int a0 = eattr[e*3], a1 = eattr[e*3+1], a2 = eattr[e*3+2];
            if (p - (d << 5) < 32)  // overflow guard (never fires for this degree dist)
                ell[p] = src[e] | ((a0 * 12 + a1 * 2 + a2) << 18);
        }
        return;
    }
    if (blockIdx.x < EMB_B0) {
        int idx = (blockIdx.x - TCB_B0) * 256 + threadIdx.x;  // < 264*128
        if (idx >= 264 * 128) return;
        int row = idx >> 7, j = idx & 127;
        int a0 = row / 12, rem = row % 12;
        int a1 = rem >> 1, a2 = rem & 1;
        Tcb[idx] = f2bf(T[a0 * 128 + j] + T[(22 + a1) * 128 + j] + T[(28 + a2) * 128 + j]);
        return;
    }
    if (blockIdx.x >= BND_B0) {
        int idx = (blockIdx.x - BND_B0) * 256 + threadIdx.x;
        if (idx < NN) {
            int b = bid[idx];
            if (idx == 0 || bid[idx - 1] != b) gstart[b] = idx;
            if (idx == NN - 1 || bid[idx + 1] != b) gend[b] = idx + 1;
        }
        return;
    }
    int g = threadIdx.x >> 5, lane = threadIdx.x & 31;
    int n = (blockIdx.x - EMB_B0) * 8 + g;
    const int offs[9] = {0,119,128,139,151,160,165,173,175};
    int c4 = lane * 4;
    float ax = 0.f, ay = 0.f, az = 0.f, aw = 0.f;
    #pragma unroll
    for (int i = 0; i < 9; ++i) {
        int xv = x[n*9 + i];
        float4 p = *(const float4*)&P[(offs[i] + xv) * 128 + c4];
        ax += p.x; ay += p.y; az += p.z; aw += p.w;
    }
    ushort4 o = {f2bf(ax), f2bf(ay), f2bf(az), f2bf(aw)};
    *(ushort4*)&h[(size_t)n*128 + c4] = o;
}

// ---------------- aggregation: s[n] = h[n] + sum relu(h[src]+Tcb[cidx]) ----------------
// 16 lanes per node, linear node order, QUAD ell reads (int4 -> 4 gathers in flight).
// Output written CHUNK-SWIZZLED (chunk = lane ^ (n&7)) so mlp can global_load_lds linearly.
__global__ __launch_bounds__(256) void agg_kernel(
    const unsigned short* __restrict__ h, const unsigned short* __restrict__ Tcb,
    const int* __restrict__ cursor, const int* __restrict__ ell,
    unsigned short* __restrict__ s)
{
    int g = threadIdx.x >> 4, lane = threadIdx.x & 15;
    int n = blockIdx.x * 16 + g;
    int st = n << 5, en = cursor[n];
    int deg = en - st;
    int lb = lane * 16;  // byte offset within 256-B row
    const char* hb = (const char*)h;
    const char* tb = (const char*)Tcb;
    const f32x2 zero = {0.f, 0.f};
    f32x2 a0 = zero, a1 = zero, a2 = zero, a3 = zero;
    f32x2 c0 = zero, c1 = zero, c2 = zero, c3 = zero;

    int p = st;
    int full = st + (deg & ~3);
    for (; p < full; p += 4) {
        int4 w = *(const int4*)&ell[p];   // uniform per group -> broadcast
        uint4 hv0 = *(const uint4*)(hb + ((size_t)(w.x & 0x3FFFF) << 8) + lb);
        uint4 hv1 = *(const uint4*)(hb + ((size_t)(w.y & 0x3FFFF) << 8) + lb);
        uint4 hv2 = *(const uint4*)(hb + ((size_t)(w.z & 0x3FFFF) << 8) + lb);
        uint4 hv3 = *(const uint4*)(hb + ((size_t)(w.w & 0x3FFFF) << 8) + lb);
        uint4 tv0 = *(const uint4*)(tb + ((w.x >> 18) << 8) + lb);
        uint4 tv1 = *(const uint4*)(tb + ((w.y >> 18) << 8) + lb);
        uint4 tv2 = *(const uint4*)(tb + ((w.z >> 18) << 8) + lb);
        uint4 tv3 = *(const uint4*)(tb + ((w.w >> 18) << 8) + lb);
        a0 += __builtin_elementwise_max(up2(hv0.x) + up2(tv0.x), zero);
        a1 += __builtin_elementwise_max(up2(hv0.y) + up2(tv0.y), zero);
        a2 += __builtin_elementwise_max(up2(hv0.z) + up2(tv0.z), zero);
        a3 += __builtin_elementwise_max(up2(hv0.w) + up2(tv0.w), zero);
        c0 += __builtin_elementwise_max(up2(hv1.x) + up2(tv1.x), zero);
        c1 += __builtin_elementwise_max(up2(hv1.y) + up2(tv1.y), zero);
        c2 += __builtin_elementwise_max(up2(hv1.z) + up2(tv1.z), zero);
        c3 += __builtin_elementwise_max(up2(hv1.w) + up2(tv1.w), zero);
        a0 += __builtin_elementwise_max(up2(hv2.x) + up2(tv2.x), zero);
        a1 += __builtin_elementwise_max(up2(hv2.y) + up2(tv2.y), zero);
        a2 += __builtin_elementwise_max(up2(hv2.z) + up2(tv2.z), zero);
        a3 += __builtin_elementwise_max(up2(hv2.w) + up2(tv2.w), zero);
        c0 += __builtin_elementwise_max(up2(hv3.x) + up2(tv3.x), zero);
        c1 += __builtin_elementwise_max(up2(hv3.y) + up2(tv3.y), zero);
        c2 += __builtin_elementwise_max(up2(hv3.z) + up2(tv3.z), zero);
        c3 += __builtin_elementwise_max(up2(hv3.w) + up2(tv3.w), zero);
    }
    if (p < en) {  // 1..3 leftover edges
        int4 w = *(const int4*)&ell[p];
        {
            uint4 hv = *(const uint4*)(hb + ((size_t)(w.x & 0x3FFFF) << 8) + lb);
            uint4 tv = *(const uint4*)(tb + ((w.x >> 18) << 8) + lb);
            a0 += __builtin_elementwise_max(up2(hv.x) + up2(tv.x), zero);
            a1 += __builtin_elementwise_max(up2(hv.y) + up2(tv.y), zero);
            a2 += __builtin_elementwise_max(up2(hv.z) + up2(tv.z), zero);
            a3 += __builtin_elementwise_max(up2(hv.w) + up2(tv.w), zero);
        }
        if (p + 1 < en) {
            uint4 hv = *(const uint4*)(hb + ((size_t)(w.y & 0x3FFFF) << 8) + lb);
            uint4 tv = *(const uint4*)(tb + ((w.y >> 18) << 8) + lb);
            c0 += __builtin_elementwise_max(up2(hv.x) + up2(tv.x), zero);
            c1 += __builtin_elementwise_max(up2(hv.y) + up2(tv.y), zero);
            c2 += __builtin_elementwise_max(up2(hv.z) + up2(tv.z), zero);
            c3 += __builtin_elementwise_max(up2(hv.w) + up2(tv.w), zero);
        }
        if (p + 2 < en) {
            uint4 hv = *(const uint4*)(hb + ((size_t)(w.z & 0x3FFFF) << 8) + lb);
            uint4 tv = *(const uint4*)(tb + ((w.z >> 18) << 8) + lb);
            a0 += __builtin_elementwise_max(up2(hv.x) + up2(tv.x), zero);
            a1 += __builtin_elementwise_max(up2(hv.y) + up2(tv.y), zero);
            a2 += __builtin_elementwise_max(up2(hv.z) + up2(tv.z), zero);
            a3 += __builtin_elementwise_max(up2(hv.w) + up2(tv.w), zero);
        }
    }
    uint4 hn = *(const uint4*)(hb + (size_t)n * 256 + lb);
    f32x2 r0 = up2(hn.x) + a0 + c0;
    f32x2 r1 = up2(hn.y) + a1 + c1;
    f32x2 r2 = up2(hn.z) + a2 + c2;
    f32x2 r3 = up2(hn.w) + a3 + c3;
    uint4 o;
    o.x = (unsigned)f2bf(r0.x) | ((unsigned)f2bf(r0.y) << 16);
    o.y = (unsigned)f2bf(r1.x) | ((unsigned)f2bf(r1.y) << 16);
    o.z = (unsigned)f2bf(r2.x) | ((unsigned)f2bf(r2.y) << 16);
    o.w = (unsigned)f2bf(r3.x) | ((unsigned)f2bf(r3.y) << 16);
    *(uint4*)((char*)s + (size_t)n * 256 + ((lane ^ (n & 7)) * 16)) = o;
}

// ---------------- MFMA MLP: h = relu(relu(s@W1+b1)@W2+b2), bf16 in/out ----------------
// s is stored pre-swizzled -> staging is a linear 16KB copy via global_load_lds DMA.
__global__ __launch_bounds__(256) void mlp_mfma_kernel(
    const unsigned short* __restrict__ sin, unsigned short* __restrict__ hout,
    const unsigned short* __restrict__ W1t, const float* __restrict__ b1,
    const unsigned short* __restrict__ W2t, const float* __restrict__ b2)
{
    __shared__ __attribute__((aligned(16))) unsigned short tile[64 * 128];  // 16 KB
    int tid = threadIdx.x;
    int r0 = blockIdx.x * 64;
    int wave = tid >> 6, lane = tid & 63;
    int q = lane >> 4, lr = lane & 15;
    int wcol0 = wave * 32;

    // stage s (pre-swizzled bf16) -> LDS via async DMA, 16 B per lane
    {
        const char* sb = (const char*)sin + (size_t)r0 * 256;
        char* tbb = (char*)tile;
        #pragma unroll
        for (int it = 0; it < 4; ++it) {
            int base = (it * 256 + wave * 64) * 16;  // wave-uniform LDS byte base
            __builtin_amdgcn_global_load_lds(
                (const __attribute__((address_space(1))) void*)(sb + base + lane * 16),
                (__attribute__((address_space(3))) void*)(tbb + base),
                16, 0, 0);
        }
    }

    bf16x8 Bf[4][2];
    #pragma unroll
    for (int ct = 0; ct < 2; ++ct) {
        #pragma unroll
        for (int ks = 0; ks < 4; ++ks)
            Bf[ks][ct] = *(const bf16x8*)&W1t[(size_t)(wcol0 + ct * 16 + lr) * 128 + ks * 32 + q * 8];
    }
    float bv[2];
    bv[0] = b1[wcol0 + lr];
    bv[1] = b1[wcol0 + 16 + lr];

    __syncthreads();

    f32x4 acc[4][2];
    #pragma unroll
    for (int rt = 0; rt < 4; ++rt)
        #pragma unroll
        for (int ct = 0; ct < 2; ++ct)
            acc[rt][ct] = (f32x4){0.f, 0.f, 0.f, 0.f};
    #pragma unroll
    for (int ks = 0; ks < 4; ++ks) {
        #pragma unroll
        for (int rt = 0; rt < 4; ++rt) {
            bf16x8 A = *(const bf16x8*)&tile[(rt * 16 + lr) * 128 + (((ks * 4 + q) ^ (lr & 7)) * 8)];
            #pragma unroll
            for (int ct = 0; ct < 2; ++ct)
                acc[rt][ct] = __builtin_amdgcn_mfma_f32_16x16x32_bf16(A, Bf[ks][ct], acc[rt][ct], 0, 0, 0);
        }
    }

    __syncthreads();

    #pragma unroll
    for (int ct = 0; ct < 2; ++ct) {
        #pragma unroll
        for (int ks = 0; ks < 4; ++ks)
            Bf[ks][ct] = *(const bf16x8*)&W2t[(size_t)(wcol0 + ct * 16 + lr) * 128 + ks * 32 + q * 8];
    }

    #pragma unroll
    for (int rt = 0; rt < 4; ++rt) {
        #pragma unroll
        for (int ct = 0; ct < 2; ++ct) {
            int col = wcol0 + ct * 16 + lr;
            int chunkc = col >> 3, cl = col & 7;
            #pragma unroll
            for (int i = 0; i < 4; ++i) {
                int row = rt * 16 + q * 4 + i;
                float z = fmaxf(acc[rt][ct][i] + bv[ct], 0.f);
                tile[row * 128 + ((chunkc ^ (row & 7)) * 8) + cl] = f2bf(z);
            }
        }
    }

    bv[0] = b2[wcol0 + lr];
    bv[1] = b2[wcol0 + 16 + lr];

    __syncthreads();

    #pragma unroll
    for (int rt = 0; rt < 4; ++rt)
        #pragma unroll
        for (int ct = 0; ct < 2; ++ct)
            acc[rt][ct] = (f32x4){0.f, 0.f, 0.f, 0.f};
    #pragma unroll
    for (int ks = 0; ks < 4; ++ks) {
        #pragma unroll
        for (int rt = 0; rt < 4; ++rt) {
            bf16x8 A = *(const bf16x8*)&tile[(rt * 16 + lr) * 128 + (((ks * 4 + q) ^ (lr & 7)) * 8)];
            #pragma unroll
            for (int ct = 0; ct < 2; ++ct)
                acc[rt][ct] = __builtin_amdgcn_mfma_f32_16x16x32_bf16(A, Bf[ks][ct], acc[rt][ct], 0, 0, 0);
        }
    }

    __syncthreads();

    #pragma unroll
    for (int rt = 0; rt < 4; ++rt) {
        #pragma unroll
        for (int ct = 0; ct < 2; ++ct) {
            int col = wcol0 + ct * 16 + lr;
            int chunkc = col >> 3, cl = col & 7;
            #pragma unroll
            for (int i = 0; i < 4; ++i) {
                int row = rt * 16 + q * 4 + i;
                float o = fmaxf(acc[rt][ct][i] + bv[ct], 0.f);
                tile[row * 128 + ((chunkc ^ (row & 7)) * 8) + cl] = f2bf(o);
            }
        }
    }

    __syncthreads();

    #pragma unroll
    for (int it = 0; it < 4; ++it) {
        int cid = it * 256 + tid;
        int r = cid >> 4, c = cid & 15;
        bf16x8 v = *(const bf16x8*)&tile[r * 128 + ((c ^ (r & 7)) * 8)];
        *(bf16x8*)&hout[(size_t)(r0 + r) * 128 + c * 8] = v;
    }
}

// ---------------- pool + proj + L2-normalize (vectorized loads) ----------------
__global__ __launch_bounds__(256) void pool_kernel(
    const unsigned short* __restrict__ h, const int* __restrict__ gstart, const int* __restrict__ gend,
    const float* __restrict__ pw, const float* __restrict__ pb, float* __restrict__ out)
{
    __shared__ float pooled[128];
    __shared__ float red[1024];
    int g = blockIdx.x, t = threadIdx.x;
    int gs = gstart[g], ge = gend[g];
    int lane = t & 31, half = t >> 5;   // 8 row-streams, 32 lanes x 4 cols
    int c4 = lane * 4;
    float ax = 0.f, ay = 0.f, az = 0.f, aw = 0.f;
    for (int r = gs + half; r < ge; r += 8) {
        ushort4 v = *(const ushort4*)&h[(size_t)r * 128 + c4];
        ax += b2f(v.x); ay += b2f(v.y); az += b2f(v.z); aw += b2f(v.w);
    }
    red[t*4+0] = ax; red[t*4+1] = ay; red[t*4+2] = az; red[t*4+3] = aw;
    __syncthreads();
    if (half < 4) {
        #pragma unroll
        for (int i = 0; i < 4; ++i) red[t*4+i] += red[(t+128)*4+i];
    }
    __syncthreads();
    if (half < 2) {
        #pragma unroll
        for (int i = 0; i < 4; ++i) red[t*4+i] += red[(t+64)*4+i];
    }
    __syncthreads();
    if (half < 1) {
        #pragma unroll
        for (int i = 0; i < 4; ++i) pooled[c4+i] = red[t*4+i] + red[(t+32)*4+i];
    }
    __syncthreads();
    float acc = pb[t];
    for (int k = 0; k < 128; ++k) acc += pooled[k] * pw[k * 256 + t];
    red[t] = acc * acc; __syncthreads();
    for (int off = 128; off > 0; off >>= 1) {
        if (t < off) red[t] += red[t + off];
        __syncthreads();
    }
    float nrm = sqrtf(red[0]);
    float scale = 1.f / fmaxf(nrm, 1e-12f);
    out[g * 256 + t] = acc * scale;
}

extern "C" void kernel_launch(void* const* d_in, const int* in_sizes, int n_in,
                              void* d_out, int out_size, void* d_ws, size_t ws_size,
                              hipStream_t stream) {
    const int* x     = (const int*)d_in[0];
    const int* eattr = (const int*)d_in[1];
    const int* eidx  = (const int*)d_in[2];
    const int* bids  = (const int*)d_in[3];
    const float* emb0 = (const float*)d_in[4];
    const float* emb1 = (const float*)d_in[5];
    const float* emb2 = (const float*)d_in[6];
    const float* emb3 = (const float*)d_in[7];
    const float* emb4 = (const float*)d_in[8];
    const float* emb5 = (const float*)d_in[9];
    const float* emb6 = (const float*)d_in[10];
    const float* emb7 = (const float*)d_in[11];
    const float* emb8 = (const float*)d_in[12];
    const float* node_w = (const float*)d_in[13];
    const float* node_b = (const float*)d_in[14];
    const float* ebond   = (const float*)d_in[15];
    const float* estereo = (const float*)d_in[16];
    const float* econj   = (const float*)d_in[17];
    const float* edge_w  = (const float*)d_in[18];
    const float* edge_b  = (const float*)d_in[19];
    const float* conv_w1 = (const float*)d_in[20];
    const float* conv_b1 = (const float*)d_in[21];
    const float* conv_w2 = (const float*)d_in[22];
    const float* conv_b2 = (const float*)d_in[23];
    const float* proj_w  = (const float*)d_in[24];
    const float* proj_b  = (const float*)d_in[25];
    float* out = (float*)d_out;

    char* ws = (char*)d_ws;
    size_t off = 0;
    auto alloc = [&](size_t bytes) -> void* {
        void* p = ws + off;
        off += (bytes + 255) / 256 * 256;
        return p;
    };
    unsigned short* h = (unsigned short*)alloc((size_t)NN * HD * 2);
    unsigned short* s = (unsigned short*)alloc((size_t)NN * HD * 2);
    float* P      = (float*)alloc(177 * 128 * 4);
    float* T      = (float*)alloc(30 * 128 * 4);
    unsigned short* Tcb = (unsigned short*)alloc(264 * 128 * 2);
    unsigned short* Wt = (unsigned short*)alloc(6 * 16384 * 2);
    int*   cursor = (int*)alloc((size_t)NN * 4);
    int*   ell    = (int*)alloc((size_t)NN * 32 * 4);   // 25.6 MB ELL
    int*   gstart = (int*)alloc((size_t)NG * 4);
    int*   gend   = (int*)alloc((size_t)NG * 4);

    const int* srcp = eidx;
    const int* dstp = eidx + NE;

    // setup elems: 26496 tables + 98304 weights + 200000 init = 324800 -> 1269 blocks
    setup_kernel<<<1269, 256, 0, stream>>>(
        emb0, emb1, emb2, emb3, emb4, emb5, emb6, emb7, emb8,
        node_w, node_b, ebond, estereo, econj, edge_w, edge_b,
        conv_w1, conv_w2, P, T, Wt, cursor, gstart, gend);

    embed_scatter_kernel<<<BND_B0 + BND_NB, 256, 0, stream>>>(
        T, Tcb, x, P, h, bids, gstart, gend,
        srcp, dstp, eattr, cursor, ell);

    for (int l = 0; l < 3; ++l) {
        agg_kernel<<<NN / 16, 256, 0, stream>>>(h, Tcb, cursor, ell, s);
        mlp_mfma_kernel<<<NN / 64, 256, 0, stream>>>(s, h,
            Wt + (size_t)(l * 2) * 16384, conv_b1 + (size_t)l * HD,
            Wt + (size_t)(l * 2 + 1) * 16384, conv_b2 + (size_t)l * HD);
    }
    pool_kernel<<<NG, 256, 0, stream>>>(h, gstart, gend, proj_w, proj_b, out);
}

// Round 14
// 373.618 us; speedup vs baseline: 1.1187x; 1.1187x over previous
//
#include <hip/hip_runtime.h>
#include <hip/hip_bf16.h>

#define NN 200000
#define NE 800000
#define NG 8192
#define HD 128
#define OD 256

typedef __attribute__((ext_vector_type(8))) short bf16x8;
typedef __attribute__((ext_vector_type(4))) float f32x4;
typedef __attribute__((ext_vector_type(2))) float f32x2;

__device__ inline unsigned short f2bf(float x) {
    unsigned u = __float_as_uint(x);
    unsigned r = u + 0x7FFFu + ((u >> 16) & 1u);
    return (unsigned short)(r >> 16);
}
__device__ inline float b2f(unsigned short u) {
    return __uint_as_float((unsigned)u << 16);
}
// unpack u32 holding two bf16 (lo,hi) -> f32x2
__device__ inline f32x2 up2(unsigned u) {
    f32x2 r;
    r.x = __uint_as_float(u << 16);
    r.y = __uint_as_float(u & 0xFFFF0000u);
    return r;
}

// ---------------- setup: P + T tables + weight transpose + init (cursor/gstart/gend) ----------------
// ranges: [0,22656) P, [22656,26496) T, [26496,124800) Wt, [124800,324800) init
__global__ void setup_kernel(
    const float* __restrict__ e0, const float* __restrict__ e1, const float* __restrict__ e2,
    const float* __restrict__ e3, const float* __restrict__ e4, const float* __restrict__ e5,
    const float* __restrict__ e6, const float* __restrict__ e7, const float* __restrict__ e8,
    const float* __restrict__ node_w, const float* __restrict__ node_b,
    const float* __restrict__ ebond, const float* __restrict__ estereo, const float* __restrict__ econj,
    const float* __restrict__ edge_w, const float* __restrict__ edge_b,
    const float* __restrict__ cw1, const float* __restrict__ cw2,
    float* __restrict__ P, float* __restrict__ T, unsigned short* __restrict__ Wt,
    int* __restrict__ cursor, int* __restrict__ gstart, int* __restrict__ gend)
{
    int idx = blockIdx.x * 256 + threadIdx.x;
    const int NP = 177 * 128;          // 22656
    const int NT = NP + 30 * 128;      // 26496
    const int NW = NT + 6 * 16384;     // 124800
    if (idx < NP) {
        int row = idx >> 7, j = idx & 127;
        const int offs[10] = {0,119,128,139,151,160,165,173,175,177};
        int i = 0;
        while (row >= offs[i+1]) ++i;
        int lv = row - offs[i];
        const float* emb;
        switch (i) {
            case 0: emb = e0; break; case 1: emb = e1; break; case 2: emb = e2; break;
            case 3: emb = e3; break; case 4: emb = e4; break; case 5: emb = e5; break;
            case 6: emb = e6; break; case 7: emb = e7; break; default: emb = e8; break;
        }
        float acc = (i == 0) ? node_b[j] : 0.f;
        const float* wcol = node_w + (i * 32) * 128 + j;
        #pragma unroll
        for (int d = 0; d < 32; ++d) acc += emb[lv*32 + d] * wcol[d*128];
        P[idx] = acc;
    } else if (idx < NT) {
        int k = idx - NP;
        int row = k >> 7, j = k & 127;
        int i, lv; const float* emb;
        if (row < 22)      { i = 0; lv = row;      emb = ebond;   }
        else if (row < 28) { i = 1; lv = row - 22; emb = estereo; }
        else               { i = 2; lv = row - 28; emb = econj;   }
        float acc = (i == 0) ? edge_b[j] : 0.f;
        const float* wcol = edge_w + (i * 32) * 128 + j;
        #pragma unroll
        for (int d = 0; d < 32; ++d) acc += emb[lv*32 + d] * wcol[d*128];
        T[k] = acc;
    } else if (idx < NW) {
        int w = idx - NT;
        int m = w >> 14;
        int rem = w & 16383;
        int j = rem >> 7, k = rem & 127;
        int l = m >> 1;
        const float* W = ((m & 1) ? cw2 : cw1) + (size_t)l * 16384;
        Wt[w] = f2bf(W[k * 128 + j]);
    } else {
        int k = idx - NW;
        if (k < NN) cursor[k] = k << 5;
        if (k < NG) { gstart[k] = NN; gend[k] = 0; }
    }
}

// ---------------- combine (blocks 0..131) + embed + bounds, one dispatch ----------------
#define EMB_B0 132
#define EMB_NB (NN / 8)           // 25000
#define BND_B0 (EMB_B0 + EMB_NB)
__global__ __launch_bounds__(256) void combine_embed_bounds_kernel(
    const float* __restrict__ T, unsigned short* __restrict__ Tcb,
    const int* __restrict__ x, const float* __restrict__ P, unsigned short* __restrict__ h,
    const int* __restrict__ bid, int* __restrict__ gstart, int* __restrict__ gend)
{
    if (blockIdx.x < EMB_B0) {
        int idx = blockIdx.x * 256 + threadIdx.x;  // < 264*128
        if (idx >= 264 * 128) return;
        int row = idx >> 7, j = idx & 127;
        int a0 = row / 12, rem = row % 12;
        int a1 = rem >> 1, a2 = rem & 1;
        Tcb[idx] = f2bf(T[a0 * 128 + j] + T[(22 + a1) * 128 + j] + T[(28 + a2) * 128 + j]);
        return;
    }
    if (blockIdx.x >= BND_B0) {
        int idx = (blockIdx.x - BND_B0) * 256 + threadIdx.x;
        if (idx < NN) {
            int b = bid[idx];
            if (idx == 0 || bid[idx - 1] != b) gstart[b] = idx;
            if (idx == NN - 1 || bid[idx + 1] != b) gend[b] = idx + 1;
        }
        return;
    }
    int g = threadIdx.x >> 5, lane = threadIdx.x & 31;
    int n = (blockIdx.x - EMB_B0) * 8 + g;
    const int offs[9] = {0,119,128,139,151,160,165,173,175};
    int c4 = lane * 4;
    float ax = 0.f, ay = 0.f, az = 0.f, aw = 0.f;
    #pragma unroll
    for (int i = 0; i < 9; ++i) {
        int xv = x[n*9 + i];
        float4 p = *(const float4*)&P[(offs[i] + xv) * 128 + c4];
        ax += p.x; ay += p.y; az += p.z; aw += p.w;
    }
    ushort4 o = {f2bf(ax), f2bf(ay), f2bf(az), f2bf(aw)};
    *(ushort4*)&h[(size_t)n*128 + c4] = o;
}

// ---------------- ELL scatter: ell[atomicAdd(cursor[dst])] = src | cidx<<18 ----------------
// 2 edges per thread (strided halves, coalesced loads); high TLP + 2x atomic ILP.
__global__ void scatter_kernel(const int* __restrict__ src, const int* __restrict__ dst,
                               const int* __restrict__ eattr, int* __restrict__ cursor,
                               int* __restrict__ ell) {
    int e0 = blockIdx.x * 256 + threadIdx.x;
    if (e0 >= NE / 2) return;
    #pragma unroll
    for (int k = 0; k < 2; ++k) {
        int e = e0 + k * (NE / 2);
        int d = dst[e];
        int p = atomicAdd(&cursor[d], 1);
        int a0 = eattr[e*3], a1 = eattr[e*3+1], a2 = eattr[e*3+2];
        if (p - (d << 5) < 32)  // overflow guard (never fires for this degree dist)
            ell[p] = src[e] | ((a0 * 12 + a1 * 2 + a2) << 18);
    }
}

// ---------------- aggregation: s[n] = h[n] + sum relu(h[src]+Tcb[cidx]) ----------------
// 16 lanes per node (16 B/lane), linear node order, unroll 2, ELL rows (st=n*32, en=cursor[n]).
// Output written CHUNK-SWIZZLED (chunk = lane ^ (n&7)) so mlp can global_load_lds linearly.
__global__ __launch_bounds__(256) void agg_kernel(
    const unsigned short* __restrict__ h, const unsigned short* __restrict__ Tcb,
    const int* __restrict__ cursor, const int* __restrict__ ell,
    unsigned short* __restrict__ s)
{
    int g = threadIdx.x >> 4, lane = threadIdx.x & 15;
    int n = blockIdx.x * 16 + g;
    int st = n << 5, en = cursor[n];
    int lb = lane * 16;  // byte offset within 256-B row
    const char* hb = (const char*)h;
    const char* tb = (const char*)Tcb;
    const f32x2 zero = {0.f, 0.f};
    f32x2 a0 = zero, a1 = zero, a2 = zero, a3 = zero;
    f32x2 c0 = zero, c1 = zero, c2 = zero, c3 = zero;
    int p = st;
    for (; p + 2 <= en; p += 2) {
        int va = ell[p];
        int vb = ell[p + 1];
        uint4 hv0 = *(const uint4*)(hb + ((size_t)(va & 0x3FFFF) << 8) + lb);
        uint4 tv0 = *(const uint4*)(tb + ((va >> 18) << 8) + lb);
        uint4 hv1 = *(const uint4*)(hb + ((size_t)(vb & 0x3FFFF) << 8) + lb);
        uint4 tv1 = *(const uint4*)(tb + ((vb >> 18) << 8) + lb);
        a0 += __builtin_elementwise_max(up2(hv0.x) + up2(tv0.x), zero);
        a1 += __builtin_elementwise_max(up2(hv0.y) + up2(tv0.y), zero);
        a2 += __builtin_elementwise_max(up2(hv0.z) + up2(tv0.z), zero);
        a3 += __builtin_elementwise_max(up2(hv0.w) + up2(tv0.w), zero);
        c0 += __builtin_elementwise_max(up2(hv1.x) + up2(tv1.x), zero);
        c1 += __builtin_elementwise_max(up2(hv1.y) + up2(tv1.y), zero);
        c2 += __builtin_elementwise_max(up2(hv1.z) + up2(tv1.z), zero);
        c3 += __builtin_elementwise_max(up2(hv1.w) + up2(tv1.w), zero);
    }
    if (p < en) {
        int va = ell[p];
        uint4 hv0 = *(const uint4*)(hb + ((size_t)(va & 0x3FFFF) << 8) + lb);
        uint4 tv0 = *(const uint4*)(tb + ((va >> 18) << 8) + lb);
        a0 += __builtin_elementwise_max(up2(hv0.x) + up2(tv0.x), zero);
        a1 += __builtin_elementwise_max(up2(hv0.y) + up2(tv0.y), zero);
        a2 += __builtin_elementwise_max(up2(hv0.z) + up2(tv0.z), zero);
        a3 += __builtin_elementwise_max(up2(hv0.w) + up2(tv0.w), zero);
    }
    uint4 hn = *(const uint4*)(hb + (size_t)n * 256 + lb);
    f32x2 r0 = up2(hn.x) + a0 + c0;
    f32x2 r1 = up2(hn.y) + a1 + c1;
    f32x2 r2 = up2(hn.z) + a2 + c2;
    f32x2 r3 = up2(hn.w) + a3 + c3;
    uint4 o;
    o.x = (unsigned)f2bf(r0.x) | ((unsigned)f2bf(r0.y) << 16);
    o.y = (unsigned)f2bf(r1.x) | ((unsigned)f2bf(r1.y) << 16);
    o.z = (unsigned)f2bf(r2.x) | ((unsigned)f2bf(r2.y) << 16);
    o.w = (unsigned)f2bf(r3.x) | ((unsigned)f2bf(r3.y) << 16);
    *(uint4*)((char*)s + (size_t)n * 256 + ((lane ^ (n & 7)) * 16)) = o;
}

// ---------------- MFMA MLP: h = relu(relu(s@W1+b1)@W2+b2), bf16 in/out ----------------
// s is stored pre-swizzled -> staging is a linear 16KB copy via global_load_lds DMA.
__global__ __launch_bounds__(256) void mlp_mfma_kernel(
    const unsigned short* __restrict__ sin, unsigned short* __restrict__ hout,
    const unsigned short* __restrict__ W1t, const float* __restrict__ b1,
    const unsigned short* __restrict__ W2t, const float* __restrict__ b2)
{
    __shared__ __attribute__((aligned(16))) unsigned short tile[64 * 128];  // 16 KB
    int tid = threadIdx.x;
    int r0 = blockIdx.x * 64;
    int wave = tid >> 6, lane = tid & 63;
    int q = lane >> 4, lr = lane & 15;
    int wcol0 = wave * 32;

    // stage s (pre-swizzled bf16) -> LDS via async DMA, 16 B per lane
    {
        const char* sb = (const char*)sin + (size_t)r0 * 256;
        char* tbb = (char*)tile;
        #pragma unroll
        for (int it = 0; it < 4; ++it) {
            int base = (it * 256 + wave * 64) * 16;  // wave-uniform LDS byte base
            __builtin_amdgcn_global_load_lds(
                (const __attribute__((address_space(1))) void*)(sb + base + lane * 16),
                (__attribute__((address_space(3))) void*)(tbb + base),
                16, 0, 0);
        }
    }

    bf16x8 Bf[4][2];
    #pragma unroll
    for (int ct = 0; ct < 2; ++ct) {
        #pragma unroll
        for (int ks = 0; ks < 4; ++ks)
            Bf[ks][ct] = *(const bf16x8*)&W1t[(size_t)(wcol0 + ct * 16 + lr) * 128 + ks * 32 + q * 8];
    }
    float bv[2];
    bv[0] = b1[wcol0 + lr];
    bv[1] = b1[wcol0 + 16 + lr];

    __syncthreads();

    f32x4 acc[4][2];
    #pragma unroll
    for (int rt = 0; rt < 4; ++rt)
        #pragma unroll
        for (int ct = 0; ct < 2; ++ct)
            acc[rt][ct] = (f32x4){0.f, 0.f, 0.f, 0.f};
    #pragma unroll
    for (int ks = 0; ks < 4; ++ks) {
        #pragma unroll
        for (int rt = 0; rt < 4; ++rt) {
            bf16x8 A = *(const bf16x8*)&tile[(rt * 16 + lr) * 128 + (((ks * 4 + q) ^ (lr & 7)) * 8)];
            #pragma unroll
            for (int ct = 0; ct < 2; ++ct)
                acc[rt][ct] = __builtin_amdgcn_mfma_f32_16x16x32_bf16(A, Bf[ks][ct], acc[rt][ct], 0, 0, 0);
        }
    }

    __syncthreads();

    #pragma unroll
    for (int ct = 0; ct < 2; ++ct) {
        #pragma unroll
        for (int ks = 0; ks < 4; ++ks)
            Bf[ks][ct] = *(const bf16x8*)&W2t[(size_t)(wcol0 + ct * 16 + lr) * 128 + ks * 32 + q * 8];
    }

    #pragma unroll
    for (int rt = 0; rt < 4; ++rt) {
        #pragma unroll
        for (int ct = 0; ct < 2; ++ct) {
            int col = wcol0 + ct * 16 + lr;
            int chunkc = col >> 3, cl = col & 7;
            #pragma unroll
            for (int i = 0; i < 4; ++i) {
                int row = rt * 16 + q * 4 + i;
                float z = fmaxf(acc[rt][ct][i] + bv[ct], 0.f);
                tile[row * 128 + ((chunkc ^ (row & 7)) * 8) + cl] = f2bf(z);
            }
        }
    }

    bv[0] = b2[wcol0 + lr];
    bv[1] = b2[wcol0 + 16 + lr];

    __syncthreads();

    #pragma unroll
    for (int rt = 0; rt < 4; ++rt)
        #pragma unroll
        for (int ct = 0; ct < 2; ++ct)
            acc[rt][ct] = (f32x4){0.f, 0.f, 0.f, 0.f};
    #pragma unroll
    for (int ks = 0; ks < 4; ++ks) {
        #pragma unroll
        for (int rt = 0; rt < 4; ++rt) {
            bf16x8 A = *(const bf16x8*)&tile[(rt * 16 + lr) * 128 + (((ks * 4 + q) ^ (lr & 7)) * 8)];
            #pragma unroll
            for (int ct = 0; ct < 2; ++ct)
                acc[rt][ct] = __builtin_amdgcn_mfma_f32_16x16x32_bf16(A, Bf[ks][ct], acc[rt][ct], 0, 0, 0);
        }
    }

    __syncthreads();

    #pragma unroll
    for (int rt = 0; rt < 4; ++rt) {
        #pragma unroll
        for (int ct = 0; ct < 2; ++ct) {
            int col = wcol0 + ct * 16 + lr;
            int chunkc = col >> 3, cl = col & 7;
            #pragma unroll
            for (int i = 0; i < 4; ++i) {
                int row = rt * 16 + q * 4 + i;
                float o = fmaxf(acc[rt][ct][i] + bv[ct], 0.f);
                tile[row * 128 + ((chunkc ^ (row & 7)) * 8) + cl] = f2bf(o);
            }
        }
    }

    __syncthreads();

    #pragma unroll
    for (int it = 0; it < 4; ++it) {
        int cid = it * 256 + tid;
        int r = cid >> 4, c = cid & 15;
        bf16x8 v = *(const bf16x8*)&tile[r * 128 + ((c ^ (r & 7)) * 8)];
        *(bf16x8*)&hout[(size_t)(r0 + r) * 128 + c * 8] = v;
    }
}

// ---------------- pool + proj + L2-normalize (vectorized loads) ----------------
__global__ __launch_bounds__(256) void pool_kernel(
    const unsigned short* __restrict__ h, const int* __restrict__ gstart, const int* __restrict__ gend,
    const float* __restrict__ pw, const float* __restrict__ pb, float* __restrict__ out)
{
    __shared__ float pooled[128];
    __shared__ float red[1024];
    int g = blockIdx.x, t = threadIdx.x;
    int gs = gstart[g], ge = gend[g];
    int lane = t & 31, half = t >> 5;   // 8 row-streams, 32 lanes x 4 cols
    int c4 = lane * 4;
    float ax = 0.f, ay = 0.f, az = 0.f, aw = 0.f;
    for (int r = gs + half; r < ge; r += 8) {
        ushort4 v = *(const ushort4*)&h[(size_t)r * 128 + c4];
        ax += b2f(v.x); ay += b2f(v.y); az += b2f(v.z); aw += b2f(v.w);
    }
    red[t*4+0] = ax; red[t*4+1] = ay; red[t*4+2] = az; red[t*4+3] = aw;
    __syncthreads();
    if (half < 4) {
        #pragma unroll
        for (int i = 0; i < 4; ++i) red[t*4+i] += red[(t+128)*4+i];
    }
    __syncthreads();
    if (half < 2) {
        #pragma unroll
        for (int i = 0; i < 4; ++i) red[t*4+i] += red[(t+64)*4+i];
    }
    __syncthreads();
    if (half < 1) {
        #pragma unroll
        for (int i = 0; i < 4; ++i) pooled[c4+i] = red[t*4+i] + red[(t+32)*4+i];
    }
    __syncthreads();
    float acc = pb[t];
    for (int k = 0; k < 128; ++k) acc += pooled[k] * pw[k * 256 + t];
    red[t] = acc * acc; __syncthreads();
    for (int off = 128; off > 0; off >>= 1) {
        if (t < off) red[t] += red[t + off];
        __syncthreads();
    }
    float nrm = sqrtf(red[0]);
    float scale = 1.f / fmaxf(nrm, 1e-12f);
    out[g * 256 + t] = acc * scale;
}

extern "C" void kernel_launch(void* const* d_in, const int* in_sizes, int n_in,
                              void* d_out, int out_size, void* d_ws, size_t ws_size,
                              hipStream_t stream) {
    const int* x     = (const int*)d_in[0];
    const int* eattr = (const int*)d_in[1];
    const int* eidx  = (const int*)d_in[2];
    const int* bids  = (const int*)d_in[3];
    const float* emb0 = (const float*)d_in[4];
    const float* emb1 = (const float*)d_in[5];
    const float* emb2 = (const float*)d_in[6];
    const float* emb3 = (const float*)d_in[7];
    const float* emb4 = (const float*)d_in[8];
    const float* emb5 = (const float*)d_in[9];
    const float* emb6 = (const float*)d_in[10];
    const float* emb7 = (const float*)d_in[11];
    const float* emb8 = (const float*)d_in[12];
    const float* node_w = (const float*)d_in[13];
    const float* node_b = (const float*)d_in[14];
    const float* ebond   = (const float*)d_in[15];
    const float* estereo = (const float*)d_in[16];
    const float* econj   = (const float*)d_in[17];
    const float* edge_w  = (const float*)d_in[18];
    const float* edge_b  = (const float*)d_in[19];
    const float* conv_w1 = (const float*)d_in[20];
    const float* conv_b1 = (const float*)d_in[21];
    const float* conv_w2 = (const float*)d_in[22];
    const float* conv_b2 = (const float*)d_in[23];
    const float* proj_w  = (const float*)d_in[24];
    const float* proj_b  = (const float*)d_in[25];
    float* out = (float*)d_out;

    char* ws = (char*)d_ws;
    size_t off = 0;
    auto alloc = [&](size_t bytes) -> void* {
        void* p = ws + off;
        off += (bytes + 255) / 256 * 256;
        return p;
    };
    unsigned short* h = (unsigned short*)alloc((size_t)NN * HD * 2);
    unsigned short* s = (unsigned short*)alloc((size_t)NN * HD * 2);
    float* P      = (float*)alloc(177 * 128 * 4);
    float* T      = (float*)alloc(30 * 128 * 4);
    unsigned short* Tcb = (unsigned short*)alloc(264 * 128 * 2);
    unsigned short* Wt = (unsigned short*)alloc(6 * 16384 * 2);
    int*   cursor = (int*)alloc((size_t)NN * 4);
    int*   ell    = (int*)alloc((size_t)NN * 32 * 4);   // 25.6 MB ELL
    int*   gstart = (int*)alloc((size_t)NG * 4);
    int*   gend   = (int*)alloc((size_t)NG * 4);

    const int NB = (NN + 255) / 256;  // 782
    const int* srcp = eidx;
    const int* dstp = eidx + NE;

    // setup elems: 26496 tables + 98304 weights + 200000 init = 324800 -> 1269 blocks
    setup_kernel<<<1269, 256, 0, stream>>>(
        emb0, emb1, emb2, emb3, emb4, emb5, emb6, emb7, emb8,
        node_w, node_b, ebond, estereo, econj, edge_w, edge_b,
        conv_w1, conv_w2, P, T, Wt, cursor, gstart, gend);

    combine_embed_bounds_kernel<<<EMB_B0 + EMB_NB + NB, 256, 0, stream>>>(
        T, Tcb, x, P, h, bids, gstart, gend);

    scatter_kernel<<<(NE / 2 + 255) / 256, 256, 0, stream>>>(srcp, dstp, eattr, cursor, ell);

    for (int l = 0; l < 3; ++l) {
        agg_kernel<<<NN / 16, 256, 0, stream>>>(h, Tcb, cursor, ell, s);
        mlp_mfma_kernel<<<NN / 64, 256, 0, stream>>>(s, h,
            Wt + (size_t)(l * 2) * 16384, conv_b1 + (size_t)l * HD,
            Wt + (size_t)(l * 2 + 1) * 16384, conv_b2 + (size_t)l * HD);
    }
    pool_kernel<<<NG, 256, 0, stream>>>(h, gstart, gend, proj_w, proj_b, out);
}